// Round 2
// baseline (502.600 us; speedup 1.0000x reference)
//
#include <hip/hip_runtime.h>
#include <hip/hip_bf16.h>

#define BB 8
#define NN 4096
#define DD 1024
#define HH 64

typedef __bf16 bf8v __attribute__((ext_vector_type(8)));
typedef __bf16 bf4v __attribute__((ext_vector_type(4)));
typedef float  f4v  __attribute__((ext_vector_type(4)));
typedef __hip_bfloat16 bf16;

__device__ __forceinline__ f4v mfma16x16x32(bf8v a, bf8v b, f4v c) {
    return __builtin_amdgcn_mfma_f32_16x16x32_bf16(a, b, c, 0, 0, 0);
}

// load 8 consecutive fp32, convert to a bf16x8 MFMA fragment slice
__device__ __forceinline__ bf8v cvt8(const float* p) {
    const f4v a = ((const f4v*)p)[0];
    const f4v b = ((const f4v*)p)[1];
    bf8v r;
    #pragma unroll
    for (int i = 0; i < 4; ++i) { r[i] = (__bf16)a[i]; r[i + 4] = (__bf16)b[i]; }
    return r;
}

__device__ __forceinline__ bf8v ldg8(const bf16* p) {
    return *(const bf8v*)p;
}

// Kernel 0: convert the 4 weight matrices (each 64x1024 or 1024x64 = 65536 fp32)
// to bf16 in workspace. Layout in cw: [Wq | Wk | Wv | Wp], original row-major layouts.
__global__ __launch_bounds__(256) void convert_weights_kernel(
    const float* __restrict__ Wq, const float* __restrict__ Wk,
    const float* __restrict__ Wv, const float* __restrict__ Wp,
    bf16* __restrict__ cw)
{
    const int idx = blockIdx.x * 256 + threadIdx.x;   // 65536 threads, 4 elems each
    const int t = idx >> 14;                          // tensor id 0..3
    const int e = (idx & 16383) * 4;
    const float* src = (t == 0) ? Wq : (t == 1) ? Wk : (t == 2) ? Wv : Wp;
    f4v x = *(const f4v*)(src + e);
    bf4v r;
    #pragma unroll
    for (int i = 0; i < 4; ++i) r[i] = (__bf16)x[i];
    *(bf4v*)(cw + t * 65536 + e) = r;
}

// Kernel 1: se[b,h] = sum_n exp(k[b,n,h]); sev[b,h] = sum_n exp(k)*v[b,n,h]
// k = key @ Wk^T + bk, v = value @ Wv^T + bv via MFMA, reduced in-register.
// Grid: 512 blocks (8 b * 64 chunks), 256 threads (4 waves, each a 16-row M-tile).
__global__ __launch_bounds__(256) void kv_reduce_kernel(
    const float* __restrict__ key, const float* __restrict__ value,
    const bf16* __restrict__ cWk, const float* __restrict__ bk,
    const bf16* __restrict__ cWv, const float* __restrict__ bv,
    float* __restrict__ se, float* __restrict__ sev)
{
    const int lane = threadIdx.x & 63;
    const int wave = threadIdx.x >> 6;
    const int cl   = lane & 15;   // A row (m) / C col (h) / B col
    const int quad = lane >> 4;
    const int b     = blockIdx.x >> 6;
    const int chunk = blockIdx.x & 63;
    const int row   = chunk * 64 + wave * 16 + cl;

    // A frag: lane reads A[m=cl][k = quad*8 + j], k-contiguous (8 fp32 = 32B)
    const float* kp = key   + ((size_t)b * NN + row) * DD + quad * 8;
    const float* vp = value + ((size_t)b * NN + row) * DD + quad * 8;
    // B frag: B[k][n=h] = W[h][k]; lane reads W[h=cl+16*ht][k = quad*8 + j] (bf16, 16B)
    const bf16* wk = cWk + (size_t)cl * DD + quad * 8;
    const bf16* wv = cWv + (size_t)cl * DD + quad * 8;

    f4v kacc[4], vacc[4];
    #pragma unroll
    for (int i = 0; i < 4; ++i) {
        kacc[i] = (f4v){0.f, 0.f, 0.f, 0.f};
        vacc[i] = (f4v){0.f, 0.f, 0.f, 0.f};
    }

    #pragma unroll 4
    for (int k0 = 0; k0 < DD; k0 += 32) {
        bf8v ak = cvt8(kp + k0);
        bf8v av = cvt8(vp + k0);
        #pragma unroll
        for (int ht = 0; ht < 4; ++ht) {
            bf8v bk8 = ldg8(wk + (size_t)ht * 16 * DD + k0);
            bf8v bv8 = ldg8(wv + (size_t)ht * 16 * DD + k0);
            kacc[ht] = mfma16x16x32(ak, bk8, kacc[ht]);
            vacc[ht] = mfma16x16x32(av, bv8, vacc[ht]);
        }
    }

    // C layout: col = cl (h), row = quad*4 + r (sequence row).
    // Reduce over rows: in-lane over r, then across quads via shfl_xor 16/32.
    #pragma unroll
    for (int ht = 0; ht < 4; ++ht) {
        const int h = ht * 16 + cl;
        const float bkh = bk[h];
        const float bvh = bv[h];
        float sep = 0.f, sevp = 0.f;
        #pragma unroll
        for (int r = 0; r < 4; ++r) {
            float e = __expf(kacc[ht][r] + bkh);
            sep  += e;
            sevp += e * (vacc[ht][r] + bvh);
        }
        sep  += __shfl_xor(sep, 16, 64);
        sevp += __shfl_xor(sevp, 16, 64);
        sep  += __shfl_xor(sep, 32, 64);
        sevp += __shfl_xor(sevp, 32, 64);
        if (quad == 0) {
            atomicAdd(&se[b * HH + h], sep);
            atomicAdd(&sev[b * HH + h], sevp);
        }
    }
}

// Kernel 2: out[b,n,:] = (sigmoid(q[b,n,:]) * w[b,:]) @ Wp^T + bp
// q via MFMA GEMM1 (K=1024); gate; LDS round-trip (C-layout -> A-layout);
// GEMM2 (K=64, Nout=1024) looping 64 d-tiles of Wp.
__global__ __launch_bounds__(256) void out_kernel(
    const float* __restrict__ query,
    const bf16* __restrict__ cWq, const float* __restrict__ bq,
    const bf16* __restrict__ cWp, const float* __restrict__ bp,
    const float* __restrict__ se, const float* __restrict__ sev,
    float* __restrict__ out)
{
    // +8 pad (stride 72) so the b128 A-frag reads don't 16-way bank-conflict
    __shared__ __align__(16) bf16 gsh[4][16][72];

    const int lane = threadIdx.x & 63;
    const int wave = threadIdx.x >> 6;
    const int cl   = lane & 15;
    const int quad = lane >> 4;
    const int b     = blockIdx.x >> 6;
    const int chunk = blockIdx.x & 63;
    const int row0  = chunk * 64 + wave * 16;

    // ---- GEMM1: q-tile (16 rows x 64 h) ----
    f4v qacc[4];
    #pragma unroll
    for (int i = 0; i < 4; ++i) qacc[i] = (f4v){0.f, 0.f, 0.f, 0.f};

    const float* qp = query + ((size_t)b * NN + row0 + cl) * DD + quad * 8;
    const bf16*  wq = cWq + (size_t)cl * DD + quad * 8;

    #pragma unroll 4
    for (int k0 = 0; k0 < DD; k0 += 32) {
        bf8v aq = cvt8(qp + k0);
        #pragma unroll
        for (int ht = 0; ht < 4; ++ht) {
            bf8v bw = ldg8(wq + (size_t)ht * 16 * DD + k0);
            qacc[ht] = mfma16x16x32(aq, bw, qacc[ht]);
        }
    }

    // ---- gate: g = sigmoid(q + bq) * (sev/se), write C-layout into LDS ----
    #pragma unroll
    for (int ht = 0; ht < 4; ++ht) {
        const int h = ht * 16 + cl;
        const float w   = sev[b * HH + h] / se[b * HH + h];
        const float bqh = bq[h];
        #pragma unroll
        for (int r = 0; r < 4; ++r) {
            float q = qacc[ht][r] + bqh;
            float s = 1.0f / (1.0f + __expf(-q));
            gsh[wave][quad * 4 + r][h] = __float2bfloat16(s * w);
        }
    }
    __syncthreads();

    // ---- re-read as A-operand frags: A[m=cl][k = kk*32 + quad*8 + j] ----
    bf8v a2[2];
    #pragma unroll
    for (int kk = 0; kk < 2; ++kk)
        a2[kk] = *(const bf8v*)&gsh[wave][cl][kk * 32 + quad * 8];

    // ---- GEMM2: loop 64 d-tiles; B[k=h][n=d] = Wp[d][h], h-contiguous 16B ----
    const bf16* wp = cWp + (size_t)cl * HH + quad * 8;
    const size_t outbase = ((size_t)b * NN + row0 + quad * 4) * DD;

    #pragma unroll 4
    for (int nt = 0; nt < 64; ++nt) {
        const int d0 = nt * 16;
        f4v o = (f4v){0.f, 0.f, 0.f, 0.f};
        o = mfma16x16x32(a2[0], ldg8(wp + (size_t)d0 * HH), o);
        o = mfma16x16x32(a2[1], ldg8(wp + (size_t)d0 * HH + 32), o);
        const int dcol = d0 + cl;
        const float bpd = bp[dcol];
        #pragma unroll
        for (int r = 0; r < 4; ++r) {
            out[outbase + (size_t)r * DD + dcol] = o[r] + bpd;
        }
    }
}

extern "C" void kernel_launch(void* const* d_in, const int* in_sizes, int n_in,
                              void* d_out, int out_size, void* d_ws, size_t ws_size,
                              hipStream_t stream)
{
    const float* query = (const float*)d_in[0];
    const float* key_  = (const float*)d_in[1];
    const float* value = (const float*)d_in[2];
    const float* Wq = (const float*)d_in[3];
    const float* bq = (const float*)d_in[4];
    const float* Wk = (const float*)d_in[5];
    const float* bk = (const float*)d_in[6];
    const float* Wv = (const float*)d_in[7];
    const float* bv = (const float*)d_in[8];
    const float* Wp = (const float*)d_in[9];
    const float* bp = (const float*)d_in[10];
    float* out = (float*)d_out;

    float* se  = (float*)d_ws;                       // 512 fp32
    float* sev = se + BB * HH;                       // 512 fp32
    bf16*  cw  = (bf16*)((char*)d_ws + 4096);        // 4 * 65536 bf16 = 512 KB

    // ws is re-poisoned to 0xAA before every launch — zero the accumulators.
    hipMemsetAsync(d_ws, 0, 2 * BB * HH * sizeof(float), stream);

    convert_weights_kernel<<<dim3(256), dim3(256), 0, stream>>>(Wq, Wk, Wv, Wp, cw);
    kv_reduce_kernel<<<dim3(512), dim3(256), 0, stream>>>(
        key_, value, cw + 1 * 65536, bk, cw + 2 * 65536, bv, se, sev);
    out_kernel<<<dim3(512), dim3(256), 0, stream>>>(
        query, cw + 0 * 65536, bq, cw + 3 * 65536, bp, se, sev, out);
}